// Round 15
// baseline (901.961 us; speedup 1.0000x reference)
//
#include <hip/hip_runtime.h>
#include <math.h>

#define TN 2048
#define DN 1024

typedef __attribute__((ext_vector_type(8))) _Float16 half8;
typedef __attribute__((ext_vector_type(4))) _Float16 half4v;
typedef __attribute__((ext_vector_type(4))) float f32x4;

__device__ __forceinline__ f32x4 mfma16(half8 a, half8 b, f32x4 c) {
  return __builtin_amdgcn_mfma_f32_16x16x32_f16(a, b, c, 0, 0, 0);
}

#define BAR_LDS()  asm volatile("s_waitcnt lgkmcnt(0)\ns_barrier" ::: "memory")
#define WAITVM0()  asm volatile("s_waitcnt vmcnt(0)" ::: "memory")

// K tile image (32 keys x 1024 feats, f16, 64KB):
//   elem_off(key,f) = (f>>4)*512 + perm(key>>2)*64 + (key&3)*16 + (f&15)
__device__ __forceinline__ int img_off(int key, int f) {
  const int kg = key >> 2;
  const int p  = ((kg & 1) << 2) | (kg >> 1);
  return (f >> 4) * 512 + p * 64 + (key & 3) * 16 + (f & 15);
}

// x fp32 -> K tile images in ws[0..32MB): [b*64+tile][32768]
__global__ __launch_bounds__(256) void convert_x(const float* __restrict__ x,
                                                 _Float16* __restrict__ w) {
  const long long gid = (long long)blockIdx.x * 256 + threadIdx.x;
  const long long e   = gid * 8;
  const int bt   = (int)(e >> 15);
  const int et   = (int)(e & 32767);
  const int f16b = et >> 9;
  const int p    = (et >> 6) & 7;
  const int row  = (et >> 4) & 3;
  const int col0 = et & 15;
  const int kg   = ((p & 3) << 1) | (p >> 2);
  const int key  = kg * 4 + row;
  const size_t xoff = ((size_t)bt * 32 + key) * DN + f16b * 16 + col0;
  float4 u0 = *(const float4*)(x + xoff);
  float4 u1 = *(const float4*)(x + xoff + 4);
  half8 h = {(_Float16)u0.x, (_Float16)u0.y, (_Float16)u0.z, (_Float16)u0.w,
             (_Float16)u1.x, (_Float16)u1.y, (_Float16)u1.z, (_Float16)u1.w};
  *(half8*)(w + e) = h;
}

// x fp32 [b][k][f] -> transposed f16 image Vt[b][f][k] in ws[32MB..64MB)
// (PV B-frags become contiguous 16B: 8 consecutive keys at fixed feat)
__global__ __launch_bounds__(256) void convert_xt(const float* __restrict__ x,
                                                  _Float16* __restrict__ vt) {
  __shared__ float tile[64][65];
  const int blk = blockIdx.x;
  const int ft  = blk & 15;          // feat tile (64 feats)
  const int kt  = (blk >> 4) & 31;   // key tile (64 keys)
  const int b   = blk >> 9;          // batch
  const int tid = threadIdx.x;
  // load 64x64 f32, coalesced
#pragma unroll
  for (int s = 0; s < 4; ++s) {
    const int r  = (tid >> 4) + s * 16;
    const int c4 = tid & 15;
    float4 v = *(const float4*)(x + ((size_t)(b * TN + kt * 64 + r)) * DN +
                                ft * 64 + c4 * 4);
    tile[r][c4 * 4 + 0] = v.x; tile[r][c4 * 4 + 1] = v.y;
    tile[r][c4 * 4 + 2] = v.z; tile[r][c4 * 4 + 3] = v.w;
  }
  __syncthreads();
  // store transposed as f16, coalesced over keys
#pragma unroll
  for (int s = 0; s < 2; ++s) {
    const int fr = (tid >> 3) + s * 32;
    const int kc = tid & 7;
    half8 h;
#pragma unroll
    for (int j = 0; j < 8; ++j) h[j] = (_Float16)tile[kc * 8 + j][fr];
    *(half8*)(vt + ((size_t)b * DN + ft * 64 + fr) * TN + kt * 64 + kc * 8) = h;
  }
}

// ================= full-L2 streaming attention (needs 64MB ws) =============
// One block = one (batch, 16-row q-tile). 8 waves, 8-way k-split QK
// (swapped mfma(K,Q)). QK A-frags: contiguous 16B from K image (L2),
// prefetched 1 iter ahead. PV B-frags: contiguous 16B from Vt image (L2),
// issued in two halves (top of iter / post-QK) -> latency hidden under
// compute. LDS = Sred roundtrip only (11KB). No staging, no tr-reads.
__global__ __launch_bounds__(512, 4)
void attn_gate2(const float* __restrict__ x, const _Float16* __restrict__ wsk,
                const _Float16* __restrict__ wsv,
                const float* __restrict__ pla, const float* __restrict__ pls,
                float* __restrict__ out) {
  __shared__ _Float16 Sred[8][16][44];   // [slice][q-row][key, pad]  11KB
  __shared__ float l_s[16], gate_s[16];

  const int tid = threadIdx.x;
  const int w   = tid >> 6;       // wave 0..7 == kq (k-eighth, 128 feats)
  const int l   = tid & 63;
  const int lr  = l & 15;
  const int lg  = l >> 4;
  const int kq  = w;

  const int b   = blockIdx.x & 7;            // batch -> XCD
  const int q16 = 127 - (blockIdx.x >> 3);   // long blocks first
  const int qbase = q16 * 16;
  const int nkt   = (qbase + 14) / 32 + 1;

  const float alpha = log1pf(expf(pla[0]));
  const float sigma = log1pf(expf(pls[0]));

  const float* xb = x + (size_t)b * TN * DN;
  float*       ob = out + (size_t)b * TN * DN;

  const _Float16* kb_img = wsk + (size_t)b * 64 * 32768;
  const _Float16* vtb    = wsv + (size_t)b * DN * TN;

  // QK A-frag offsets within a tile image: keys lr and 16+lr
  const int kg0 = lr >> 2;
  const int bk0 = ((((kg0 & 1) << 2) | (kg0 >> 1)) << 6) + (lr & 3) * 16 + (lg & 1) * 8;
  const int kg1 = 4 + (lr >> 2);
  const int bk1 = ((((kg1 & 1) << 2) | (kg1 >> 1)) << 6) + (lr & 3) * 16 + (lg & 1) * 8;

  // ---- Q fragments: row lr of this tile, k-eighth (16 VGPR) ----
  half8 qf[4];
  {
    const _Float16* qtile = kb_img + (size_t)(q16 >> 1) * 32768;
    const int qrow = (q16 & 1) * 16 + lr;
    const int g0   = qrow >> 2;
    const int qp   = (((g0 & 1) << 2) | (g0 >> 1)) * 64 + (qrow & 3) * 16 + (lg & 1) * 8;
#pragma unroll
    for (int s = 0; s < 4; ++s)
      qf[s] = *(const half8*)&qtile[(kq * 8 + s * 2 + (lg >> 1)) * 512 + qp];
  }

  // PV B-frag row bases in Vt (loop-invariant part)
  const _Float16* vrow0 = vtb + (size_t)(w * 128 + lr) * TN + lg * 8;

  f32x4 oacc[8];
#pragma unroll
  for (int ct = 0; ct < 8; ++ct) oacc[ct] = f32x4{0.f, 0.f, 0.f, 0.f};
  float l0 = 0.0f;

  // ---- prefetch QK A-frags for tile 0 ----
  half8 af0[4], af1[4];
#pragma unroll
  for (int s = 0; s < 4; ++s) {
    const int base = (kq * 8 + s * 2 + (lg >> 1)) * 512;
    af0[s] = *(const half8*)&kb_img[base + bk0];
    af1[s] = *(const half8*)&kb_img[base + bk1];
  }

  for (int t = 0; t < nkt; ++t) {
    // ---- issue PV B-frags, first half (ct 0..3) — covered by QK+exp ----
    half8 bfvA[4];
#pragma unroll
    for (int ct = 0; ct < 4; ++ct)
      bfvA[ct] = *(const half8*)&vrow0[(size_t)(ct * 16) * TN + 32 * t];

    // ---- QK^T (swapped): A = prefetched K frags, B = qf ----
    f32x4 sA = f32x4{0.f,0.f,0.f,0.f};
    f32x4 sB = f32x4{0.f,0.f,0.f,0.f};
#pragma unroll
    for (int s = 0; s < 4; ++s) {
      sA = mfma16(af0[s], qf[s], sA);
      sB = mfma16(af1[s], qf[s], sB);
    }

    // ---- issue PV B-frags, second half; then prefetch af(t+1) ----
    half8 bfvB[4];
#pragma unroll
    for (int ct = 0; ct < 4; ++ct)
      bfvB[ct] = *(const half8*)&vrow0[(size_t)((4 + ct) * 16) * TN + 32 * t];
    if (t + 1 < nkt) {
      const _Float16* tp = kb_img + (size_t)(t + 1) * 32768;
#pragma unroll
      for (int s = 0; s < 4; ++s) {
        const int base = (kq * 8 + s * 2 + (lg >> 1)) * 512;
        af0[s] = *(const half8*)&tp[base + bk0];
        af1[s] = *(const half8*)&tp[base + bk1];
      }
    }

    // ---- Sred write: lane -> 4 consecutive keys of q-row lr ----
    {
      half4v hA = {(_Float16)sA[0], (_Float16)sA[1], (_Float16)sA[2], (_Float16)sA[3]};
      half4v hB = {(_Float16)sB[0], (_Float16)sB[1], (_Float16)sB[2], (_Float16)sB[3]};
      *(half4v*)&Sred[kq][lr][lg * 4]      = hA;
      *(half4v*)&Sred[kq][lr][16 + lg * 4] = hB;
    }
    BAR_LDS();   // (A) Sred ready

    // ---- fused exp + PV ----
    {
      half8 sum = *(const half8*)&Sred[0][lr][lg * 8];
      sum = sum + *(const half8*)&Sred[1][lr][lg * 8];
      sum = sum + *(const half8*)&Sred[2][lr][lg * 8];
      sum = sum + *(const half8*)&Sred[3][lr][lg * 8];
      sum = sum + *(const half8*)&Sred[4][lr][lg * 8];
      sum = sum + *(const half8*)&Sred[5][lr][lg * 8];
      sum = sum + *(const half8*)&Sred[6][lr][lg * 8];
      sum = sum + *(const half8*)&Sred[7][lr][lg * 8];

      const bool mt = (t == nkt - 1);
      const int  gb = 32 * t + lg * 8;
      half8 aP;
#pragma unroll
      for (int j = 0; j < 8; ++j) {
        float p = __expf((float)sum[j] * 0.03125f);
        if (mt && (gb + j >= qbase + lr)) p = 0.0f;   // strictly-causal
        l0 += p;
        aP[j] = (_Float16)p;
      }

#pragma unroll
      for (int ct = 0; ct < 4; ++ct)
        oacc[ct] = mfma16(aP, bfvA[ct], oacc[ct]);
#pragma unroll
      for (int ct = 0; ct < 4; ++ct)
        oacc[4 + ct] = mfma16(aP, bfvB[ct], oacc[4 + ct]);
    }
    BAR_LDS();   // (B) Sred free for next QK's writes
  }

  // ---- l reduce ----
  {
    float lt = l0 + __shfl_xor(l0, 16);
    lt += __shfl_xor(lt, 32);
    if (w == 0 && lg == 0) l_s[lr] = lt;
  }

  // ---- epilogue: per-row <x,O>, |x|^2, |O|^2 (per-wave 128-feat slice) ----
  {
    float* ered = (float*)&Sred[0][0][0];
#pragma unroll
    for (int j = 0; j < 4; ++j) {
      const int row = lg * 4 + j;
      const float* xr = xb + (size_t)(qbase + row) * DN + w * 128 + lr;
      float a1 = 0.f, a2 = 0.f, a3 = 0.f;
#pragma unroll
      for (int ct = 0; ct < 8; ++ct) {
        const float xv = xr[ct * 16];
        const float ov = oacc[ct][j];
        a1 += xv * ov; a2 += xv * xv; a3 += ov * ov;
      }
#pragma unroll
      for (int d = 1; d < 16; d <<= 1) {
        a1 += __shfl_xor(a1, d);
        a2 += __shfl_xor(a2, d);
        a3 += __shfl_xor(a3, d);
      }
      if (lr == 0) {
        float* e = ered + (row * 8 + w) * 4;
        e[0] = a1; e[1] = a2; e[2] = a3;
      }
    }
  }
  __syncthreads();
  if (tid < 16) {
    const float* ered = (const float*)&Sred[0][0][0];
    float SxO = 0.f, Sxx = 0.f, SOO = 0.f;
#pragma unroll
    for (int wv = 0; wv < 8; ++wv) {
      const float* e = ered + (tid * 8 + wv) * 4;
      SxO += e[0]; Sxx += e[1]; SOO += e[2];
    }
    const float lden = l_s[tid];
    float cosv = 0.0f;
    if (lden > 0.0f) {
      const float nx = fmaxf(sqrtf(Sxx), 1e-12f);
      const float nc = fmaxf(sqrtf(SOO) / lden, 1e-12f);
      cosv = (SxO / lden) / (nx * nc);
    }
    float nov = fminf(fmaxf(1.0f - cosv, 0.0f), 2.0f) * 0.5f;
    gate_s[tid] = 1.0f + alpha * tanhf(sigma * nov);
  }
  __syncthreads();
  {
#pragma unroll
    for (int j = 0; j < 4; ++j) {
      const int row = lg * 4 + j;
      const float g = gate_s[row];
      const float* xr = xb + (size_t)(qbase + row) * DN + w * 128 + lr;
      float* orow     = ob + (size_t)(qbase + row) * DN + w * 128 + lr;
#pragma unroll
      for (int ct = 0; ct < 8; ++ct) {
        const float z = xr[ct * 16] * g;
        const float u = 0.7978845608028654f * (z + 0.044715f * z * z * z);
        orow[ct * 16] = 0.5f * z * (1.0f + tanhf(u));
      }
    }
  }
}

// ================= R13 kernel (mid path: 32MB ws) + fallback ===============
#define ISSUE4(T, O0, O1, O2, O3)                                             \
  asm volatile("ds_read_b64_tr_b16 %0, %4 offset:" O0 "\n\t"                  \
               "ds_read_b64_tr_b16 %1, %4 offset:" O1 "\n\t"                  \
               "ds_read_b64_tr_b16 %2, %4 offset:" O2 "\n\t"                  \
               "ds_read_b64_tr_b16 %3, %4 offset:" O3                         \
               : "=&v"(T[0]), "=&v"(T[1]), "=&v"(T[2]), "=&v"(T[3])           \
               : "v"(ab));

#define MFMA2(T, CT0, CT1)                                                    \
  {                                                                           \
    half8 bf0 = __builtin_shufflevector(T[0], T[1], 0, 1, 2, 3, 4, 5, 6, 7);  \
    half8 bf1 = __builtin_shufflevector(T[2], T[3], 0, 1, 2, 3, 4, 5, 6, 7);  \
    oacc[CT0] = mfma16(aP, bf0, oacc[CT0]);                                   \
    oacc[CT1] = mfma16(aP, bf1, oacc[CT1]);                                   \
  }

template <bool WS>
__global__ __launch_bounds__(512, 4)
void attn_gate(const float* __restrict__ x, const _Float16* __restrict__ wsx,
               const float* __restrict__ pla, const float* __restrict__ pls,
               float* __restrict__ out) {
  __shared__ _Float16 Kbuf[32768];
  __shared__ _Float16 Sred[8][16][44];
  __shared__ float l_s[16], gate_s[16];

  const int tid = threadIdx.x;
  const int w   = tid >> 6;
  const int l   = tid & 63;
  const int lr  = l & 15;
  const int lg  = l >> 4;
  const int kq  = w;

  const int b   = blockIdx.x & 7;
  const int q16 = 127 - (blockIdx.x >> 3);
  const int qbase = q16 * 16;
  const int nkt   = (qbase + 14) / 32 + 1;

  const float alpha = log1pf(expf(pla[0]));
  const float sigma = log1pf(expf(pls[0]));

  const float* xb = x + (size_t)b * TN * DN;
  float*       ob = out + (size_t)b * TN * DN;

  const int kg0 = lr >> 2;
  const int bk0 = ((((kg0 & 1) << 2) | (kg0 >> 1)) << 6) + (lr & 3) * 16 + (lg & 1) * 8;
  const int kg1 = 4 + (lr >> 2);
  const int bk1 = ((((kg1 & 1) << 2) | (kg1 >> 1)) << 6) + (lr & 3) * 16 + (lg & 1) * 8;

  auto STAGE = [&](int t) {
    if constexpr (WS) {
      const _Float16* tn = wsx + (size_t)(b * 64 + t) * 32768;
#pragma unroll
      for (int i = 0; i < 8; ++i)
        __builtin_amdgcn_global_load_lds(
            (const __attribute__((address_space(1))) void*)(tn + w * 4096 + i * 512 + l * 8),
            (__attribute__((address_space(3))) void*)(&Kbuf[w * 4096 + i * 512]), 16, 0, 0);
    } else {
      const int skey = tid >> 4, sc = tid & 15;
      const float* kp = xb + (size_t)(t * 32 + skey) * DN + sc * 4;
#pragma unroll
      for (int j = 0; j < 16; ++j) {
        const int f = sc * 4 + 64 * j;
        float4 v = *(const float4*)(kp + 64 * j);
        half4v h = {(_Float16)v.x, (_Float16)v.y, (_Float16)v.z, (_Float16)v.w};
        *(half4v*)&Kbuf[img_off(skey, f)] = h;
      }
    }
  };

  STAGE(0);

  half8 qf[4];
  if constexpr (WS) {
    const _Float16* qtile = wsx + (size_t)(b * 64 + (q16 >> 1)) * 32768;
    const int qrow = (q16 & 1) * 16 + lr;
    const int g0   = qrow >> 2;
    const int qp   = (((g0 & 1) << 2) | (g0 >> 1)) * 64 + (qrow & 3) * 16 + (lg & 1) * 8;
#pragma unroll
    for (int s = 0; s < 4; ++s)
      qf[s] = *(const half8*)&qtile[(kq * 8 + s * 2 + (lg >> 1)) * 512 + qp];
  } else {
#pragma unroll
    for (int s = 0; s < 4; ++s) {
      const float* qp = xb + (size_t)(qbase + lr) * DN + kq * 128 + s * 32 + lg * 8;
      float4 a = ((const float4*)qp)[0];
      float4 c = ((const float4*)qp)[1];
      half8 h;
      h[0]=(_Float16)a.x; h[1]=(_Float16)a.y; h[2]=(_Float16)a.z; h[3]=(_Float16)a.w;
      h[4]=(_Float16)c.x; h[5]=(_Float16)c.y; h[6]=(_Float16)c.z; h[7]=(_Float16)c.w;
      qf[s] = h;
    }
  }

  f32x4 oacc[8];
#pragma unroll
  for (int ct = 0; ct < 8; ++ct) oacc[ct] = f32x4{0.f, 0.f, 0.f, 0.f};
  float l0 = 0.0f;

  if constexpr (!WS) __syncthreads();

  for (int t = 0; t < nkt; ++t) {
    if constexpr (WS) WAITVM0();

    {
      f32x4 sA = f32x4{0.f,0.f,0.f,0.f};
      f32x4 sB = f32x4{0.f,0.f,0.f,0.f};
#pragma unroll
      for (int s = 0; s < 4; ++s) {
        const int base = (kq * 8 + s * 2 + (lg >> 1)) * 512;
        half8 bf0 = *(const half8*)&Kbuf[base + bk0];
        half8 bf1 = *(const half8*)&Kbuf[base + bk1];
        sA = mfma16(bf0, qf[s], sA);
        sB = mfma16(bf1, qf[s], sB);
      }
      half4v hA = {(_Float16)sA[0], (_Float16)sA[1], (_Float16)sA[2], (_Float16)sA[3]};
      half4v hB = {(_Float16)sB[0], (_Float16)sB[1], (_Float16)sB[2], (_Float16)sB[3]};
      *(half4v*)&Sred[kq][lr][lg * 4]      = hA;
      *(half4v*)&Sred[kq][lr][16 + lg * 4] = hB;
    }
    BAR_LDS();

    {
      half8 sum = *(const half8*)&Sred[0][lr][lg * 8];
      sum = sum + *(const half8*)&Sred[1][lr][lg * 8];
      sum = sum + *(const half8*)&Sred[2][lr][lg * 8];
      sum = sum + *(const half8*)&Sred[3][lr][lg * 8];
      sum = sum + *(const half8*)&Sred[4][lr][lg * 8];
      sum = sum + *(const half8*)&Sred[5][lr][lg * 8];
      sum = sum + *(const half8*)&Sred[6][lr][lg * 8];
      sum = sum + *(const half8*)&Sred[7][lr][lg * 8];

      const bool mt = (t == nkt - 1);
      const int  gb = 32 * t + lg * 8;
      half8 aP;
#pragma unroll
      for (int j = 0; j < 8; ++j) {
        float p = __expf((float)sum[j] * 0.03125f);
        if (mt && (gb + j >= qbase + lr)) p = 0.0f;
        l0 += p;
        aP[j] = (_Float16)p;
      }

      const uint32_t ab = (uint32_t)(uintptr_t)(void*)&Kbuf[w * 4096 + l * 4];
      asm volatile("s_waitcnt lgkmcnt(0)" ::: "memory");
      __builtin_amdgcn_sched_barrier(0);
      half4v t0[4], t1[4];
      ISSUE4(t0, "0", "512", "1024", "1536");
      ISSUE4(t1, "2048", "2560", "3072", "3584");
      asm volatile("s_waitcnt lgkmcnt(4)" ::: "memory");
      __builtin_amdgcn_sched_barrier(0);
      MFMA2(t0, 0, 1);
      ISSUE4(t0, "4096", "4608", "5120", "5632");
      asm volatile("s_waitcnt lgkmcnt(4)" ::: "memory");
      __builtin_amdgcn_sched_barrier(0);
      MFMA2(t1, 2, 3);
      ISSUE4(t1, "6144", "6656", "7168", "7680");
      asm volatile("s_waitcnt lgkmcnt(4)" ::: "memory");
      __builtin_amdgcn_sched_barrier(0);
      MFMA2(t0, 4, 5);
      asm volatile("s_waitcnt lgkmcnt(0)" ::: "memory");
      __builtin_amdgcn_sched_barrier(0);
      MFMA2(t1, 6, 7);
    }

    if (t + 1 < nkt) {
      if constexpr (!WS) __syncthreads();
      STAGE(t + 1);
    }
    BAR_LDS();
  }

  {
    float lt = l0 + __shfl_xor(l0, 16);
    lt += __shfl_xor(lt, 32);
    if (w == 0 && lg == 0) l_s[lr] = lt;
  }

  {
    float* ered = (float*)&Sred[0][0][0];
#pragma unroll
    for (int j = 0; j < 4; ++j) {
      const int row = lg * 4 + j;
      const float* xr = xb + (size_t)(qbase + row) * DN + w * 128 + lr;
      float a1 = 0.f, a2 = 0.f, a3 = 0.f;
#pragma unroll
      for (int ct = 0; ct < 8; ++ct) {
        const float xv = xr[ct * 16];
        const float ov = oacc[ct][j];
        a1 += xv * ov; a2 += xv * xv; a3 += ov * ov;
      }
#pragma unroll
      for (int d = 1; d < 16; d <<= 1) {
        a1 += __shfl_xor(a1, d);
        a2 += __shfl_xor(a2, d);
        a3 += __shfl_xor(a3, d);
      }
      if (lr == 0) {
        float* e = ered + (row * 8 + w) * 4;
        e[0] = a1; e[1] = a2; e[2] = a3;
      }
    }
  }
  __syncthreads();
  if (tid < 16) {
    const float* ered = (const float*)&Sred[0][0][0];
    float SxO = 0.f, Sxx = 0.f, SOO = 0.f;
#pragma unroll
    for (int wv = 0; wv < 8; ++wv) {
      const float* e = ered + (tid * 8 + wv) * 4;
      SxO += e[0]; Sxx += e[1]; SOO += e[2];
    }
    const float lden = l_s[tid];
    float cosv = 0.0f;
    if (lden > 0.0f) {
      const float nx = fmaxf(sqrtf(Sxx), 1e-12f);
      const float nc = fmaxf(sqrtf(SOO) / lden, 1e-12f);
      cosv = (SxO / lden) / (nx * nc);
    }
    float nov = fminf(fmaxf(1.0f - cosv, 0.0f), 2.0f) * 0.5f;
    gate_s[tid] = 1.0f + alpha * tanhf(sigma * nov);
  }
  __syncthreads();
  {
#pragma unroll
    for (int j = 0; j < 4; ++j) {
      const int row = lg * 4 + j;
      const float g = gate_s[row];
      const float* xr = xb + (size_t)(qbase + row) * DN + w * 128 + lr;
      float* orow     = ob + (size_t)(qbase + row) * DN + w * 128 + lr;
#pragma unroll
      for (int ct = 0; ct < 8; ++ct) {
        const float z = xr[ct * 16] * g;
        const float u = 0.7978845608028654f * (z + 0.044715f * z * z * z);
        orow[ct * 16] = 0.5f * z * (1.0f + tanhf(u));
      }
    }
  }
}

extern "C" void kernel_launch(void* const* d_in, const int* in_sizes, int n_in,
                              void* d_out, int out_size, void* d_ws, size_t ws_size,
                              hipStream_t stream) {
  const float* x  = (const float*)d_in[0];
  const float* la = (const float*)d_in[1];
  const float* ls = (const float*)d_in[2];
  float* out = (float*)d_out;
  const size_t needK = (size_t)8 * 64 * 32768 * 2;       // 32 MB K images
  const size_t needV = (size_t)8 * DN * TN * 2;          // 32 MB Vt image
  if (ws_size >= needK + needV) {
    _Float16* wsk = (_Float16*)d_ws;
    _Float16* wsv = (_Float16*)((char*)d_ws + needK);
    convert_x<<<dim3(8192), dim3(256), 0, stream>>>(x, wsk);
    convert_xt<<<dim3(4096), dim3(256), 0, stream>>>(x, wsv);
    attn_gate2<<<dim3(1024), dim3(512), 0, stream>>>(x, wsk, wsv, la, ls, out);
  } else if (ws_size >= needK) {
    convert_x<<<dim3(8192), dim3(256), 0, stream>>>(x, (_Float16*)d_ws);
    attn_gate<true><<<dim3(1024), dim3(512), 0, stream>>>(
        x, (const _Float16*)d_ws, la, ls, out);
  } else {
    attn_gate<false><<<dim3(1024), dim3(512), 0, stream>>>(
        x, (const _Float16*)nullptr, la, ls, out);
  }
}

// Round 16
// 212.983 us; speedup vs baseline: 4.2349x; 4.2349x over previous
//
#include <hip/hip_runtime.h>
#include <math.h>

#define TN 2048
#define DN 1024

typedef __attribute__((ext_vector_type(8))) _Float16 half8;
typedef __attribute__((ext_vector_type(4))) _Float16 half4v;
typedef __attribute__((ext_vector_type(4))) float f32x4;

__device__ __forceinline__ f32x4 mfma16(half8 a, half8 b, f32x4 c) {
  return __builtin_amdgcn_mfma_f32_16x16x32_f16(a, b, c, 0, 0, 0);
}

// lgkm-only barrier: vmem staging is synced per-wave (segment-private), never
// drained at barriers.
#define BAR_LDS()  asm volatile("s_waitcnt lgkmcnt(0)\ns_barrier" ::: "memory")
#define WAITVM0()  asm volatile("s_waitcnt vmcnt(0)" ::: "memory")

// K tile image (32 keys x 1024 feats, f16, 64KB):
//   elem_off(key,f) = (f>>4)*512 + perm(key>>2)*64 + (key&3)*16 + (f&15)
//   perm(kg) = (kg&1)*4 + (kg>>1)   (tr_read lane-group lg sees keys 8*lg+j)
// Wave w's QK reads, PV tr-reads AND staging writes all live in elems
// [w*4096,(w+1)*4096) -> K staging syncs per-wave via vmcnt, no barrier.
__device__ __forceinline__ int img_off(int key, int f) {
  const int kg = key >> 2;
  const int p  = ((kg & 1) << 2) | (kg >> 1);
  return (f >> 4) * 512 + p * 64 + (key & 3) * 16 + (f & 15);
}

// x fp32 [8][2048][1024] -> f16 tile images in ws: [b*64+tile][32768 elems]
__global__ __launch_bounds__(256) void convert_x(const float* __restrict__ x,
                                                 _Float16* __restrict__ w) {
  const long long gid = (long long)blockIdx.x * 256 + threadIdx.x;
  const long long e   = gid * 8;
  const int bt   = (int)(e >> 15);
  const int et   = (int)(e & 32767);
  const int f16b = et >> 9;
  const int p    = (et >> 6) & 7;
  const int row  = (et >> 4) & 3;
  const int col0 = et & 15;
  const int kg   = ((p & 3) << 1) | (p >> 2);    // inverse perm
  const int key  = kg * 4 + row;
  const size_t xoff = ((size_t)bt * 32 + key) * DN + f16b * 16 + col0;
  float4 u0 = *(const float4*)(x + xoff);
  float4 u1 = *(const float4*)(x + xoff + 4);
  half8 h = {(_Float16)u0.x, (_Float16)u0.y, (_Float16)u0.z, (_Float16)u0.w,
             (_Float16)u1.x, (_Float16)u1.y, (_Float16)u1.z, (_Float16)u1.w};
  *(half8*)(w + e) = h;
}

#define ISSUE4(T, O0, O1, O2, O3)                                             \
  asm volatile("ds_read_b64_tr_b16 %0, %4 offset:" O0 "\n\t"                  \
               "ds_read_b64_tr_b16 %1, %4 offset:" O1 "\n\t"                  \
               "ds_read_b64_tr_b16 %2, %4 offset:" O2 "\n\t"                  \
               "ds_read_b64_tr_b16 %3, %4 offset:" O3                         \
               : "=&v"(T[0]), "=&v"(T[1]), "=&v"(T[2]), "=&v"(T[3])           \
               : "v"(ab));

#define MFMA2(T, CT0, CT1)                                                    \
  {                                                                           \
    half8 bf0 = __builtin_shufflevector(T[0], T[1], 0, 1, 2, 3, 4, 5, 6, 7);  \
    half8 bf1 = __builtin_shufflevector(T[2], T[3], 0, 1, 2, 3, 4, 5, 6, 7);  \
    oacc[CT0] = mfma16(aP, bf0, oacc[CT0]);                                   \
    oacc[CT1] = mfma16(aP, bf1, oacc[CT1]);                                   \
  }

// One block = one (batch, 16-row q-tile). 1024 blocks, q16 descending.
// 8 waves, 8-way k-split QK (swapped mfma(K,Q)). No-max softmax.
// R16 = R13 + DOUBLE-BUFFERED Sred -> ONE barrier per K-tile:
//   [vmwait; QK(t)->SredD[t&1]] BAR [PV(t) reads SredD[t&1]; stage(t+1)]
// Hazard audit: all waves past BAR(t) => PV(t-1) reads of SredD[(t-1)&1]
// complete => QK(t+1) may overwrite it barrier-free. Kbuf sync stays
// wave-private (segment property, R8). LDS = 64K Kbuf + 16K SredD = 80K
// exactly -> 2 blocks/CU; l/gate/ered scratch aliased into SredD (post-loop).
template <bool WS>
__global__ __launch_bounds__(512, 4)
void attn_gate(const float* __restrict__ x, const _Float16* __restrict__ wsx,
               const float* __restrict__ pla, const float* __restrict__ pls,
               float* __restrict__ out) {
  __shared__ _Float16 Kbuf[32768];           // single K tile image   64KB
  __shared__ _Float16 SredD[2][8][16][32];   // dbuf S partials       16KB
  // post-loop scratch aliased into SredD (used only after BAR):
  float* l_s    = (float*)&SredD[0][0][0][0];        // 16 floats
  float* gate_s = l_s + 16;                          // 16 floats
  float* ered   = gate_s + 16;                       // 512 floats

  const int tid = threadIdx.x;
  const int w   = tid >> 6;       // wave 0..7 == kq (k-eighth, 128 feats)
  const int l   = tid & 63;
  const int lr  = l & 15;
  const int lg  = l >> 4;
  const int kq  = w;

  const int b   = blockIdx.x & 7;            // batch -> XCD
  const int q16 = 127 - (blockIdx.x >> 3);   // long blocks dispatched first
  const int qbase = q16 * 16;
  const int nkt   = (qbase + 14) / 32 + 1;   // 32-key tiles, strictly causal

  const float alpha = log1pf(expf(pla[0]));
  const float sigma = log1pf(expf(pls[0]));

  const float* xb = x + (size_t)b * TN * DN;
  float*       ob = out + (size_t)b * TN * DN;

  // QK A-frag offsets (K as A-operand): keys lr and 16+lr
  const int kg0 = lr >> 2;
  const int bk0 = ((((kg0 & 1) << 2) | (kg0 >> 1)) << 6) + (lr & 3) * 16 + (lg & 1) * 8;
  const int kg1 = 4 + (lr >> 2);
  const int bk1 = ((((kg1 & 1) << 2) | (kg1 >> 1)) << 6) + (lr & 3) * 16 + (lg & 1) * 8;

  auto STAGE = [&](int t) {   // WS: wave w writes ONLY its own segment
    if constexpr (WS) {
      const _Float16* tn = wsx + (size_t)(b * 64 + t) * 32768;
#pragma unroll
      for (int i = 0; i < 8; ++i)
        __builtin_amdgcn_global_load_lds(
            (const __attribute__((address_space(1))) void*)(tn + w * 4096 + i * 512 + l * 8),
            (__attribute__((address_space(3))) void*)(&Kbuf[w * 4096 + i * 512]), 16, 0, 0);
    } else {
      const int skey = tid >> 4, sc = tid & 15;
      const float* kp = xb + (size_t)(t * 32 + skey) * DN + sc * 4;
#pragma unroll
      for (int j = 0; j < 16; ++j) {
        const int f = sc * 4 + 64 * j;
        float4 v = *(const float4*)(kp + 64 * j);
        half4v h = {(_Float16)v.x, (_Float16)v.y, (_Float16)v.z, (_Float16)v.w};
        *(half4v*)&Kbuf[img_off(skey, f)] = h;
      }
    }
  };

  STAGE(0);

  // ---- Q fragments: row lr of this 16-row tile, k-eighth (16 VGPR) ----
  half8 qf[4];
  if constexpr (WS) {
    const _Float16* qtile = wsx + (size_t)(b * 64 + (q16 >> 1)) * 32768;
    const int qrow = (q16 & 1) * 16 + lr;
    const int g0   = qrow >> 2;
    const int qp   = (((g0 & 1) << 2) | (g0 >> 1)) * 64 + (qrow & 3) * 16 + (lg & 1) * 8;
#pragma unroll
    for (int s = 0; s < 4; ++s)
      qf[s] = *(const half8*)&qtile[(kq * 8 + s * 2 + (lg >> 1)) * 512 + qp];
  } else {
#pragma unroll
    for (int s = 0; s < 4; ++s) {
      const float* qp = xb + (size_t)(qbase + lr) * DN + kq * 128 + s * 32 + lg * 8;
      float4 a = ((const float4*)qp)[0];
      float4 c = ((const float4*)qp)[1];
      half8 h;
      h[0]=(_Float16)a.x; h[1]=(_Float16)a.y; h[2]=(_Float16)a.z; h[3]=(_Float16)a.w;
      h[4]=(_Float16)c.x; h[5]=(_Float16)c.y; h[6]=(_Float16)c.z; h[7]=(_Float16)c.w;
      qf[s] = h;
    }
  }

  f32x4 oacc[8];
#pragma unroll
  for (int ct = 0; ct < 8; ++ct) oacc[ct] = f32x4{0.f, 0.f, 0.f, 0.f};
  float l0 = 0.0f;

  if constexpr (!WS) __syncthreads();   // fallback staging is cross-segment

  for (int t = 0; t < nkt; ++t) {
    if constexpr (WS) WAITVM0();   // own-segment stage(t) landed

    // ---- QK^T (swapped): D[key_local][q-row]; lane -> 4 consecutive keys ----
    {
      f32x4 sA = f32x4{0.f,0.f,0.f,0.f};   // keys 0..15
      f32x4 sB = f32x4{0.f,0.f,0.f,0.f};   // keys 16..31
#pragma unroll
      for (int s = 0; s < 4; ++s) {
        const int base = (kq * 8 + s * 2 + (lg >> 1)) * 512;
        half8 bf0 = *(const half8*)&Kbuf[base + bk0];
        half8 bf1 = *(const half8*)&Kbuf[base + bk1];
        sA = mfma16(bf0, qf[s], sA);
        sB = mfma16(bf1, qf[s], sB);
      }
      half4v hA = {(_Float16)sA[0], (_Float16)sA[1], (_Float16)sA[2], (_Float16)sA[3]};
      half4v hB = {(_Float16)sB[0], (_Float16)sB[1], (_Float16)sB[2], (_Float16)sB[3]};
      *(half4v*)&SredD[t & 1][kq][lr][lg * 4]      = hA;   // keys lg*4..+3
      *(half4v*)&SredD[t & 1][kq][lr][16 + lg * 4] = hB;   // keys 16+lg*4..+3
    }
    BAR_LDS();   // (A) SredD[t&1] ready — the ONLY barrier per tile

    // ---- fused exp + PV (tr groups 1+2 issued early: latency hides under
    //      Sred reads + exp) ----
    {
      const uint32_t ab = (uint32_t)(uintptr_t)(void*)&Kbuf[w * 4096 + l * 4];
      half4v t0[4], t1[4];
      ISSUE4(t0, "0", "512", "1024", "1536");
      ISSUE4(t1, "2048", "2560", "3072", "3584");

      const _Float16* sp = &SredD[t & 1][0][lr][lg * 8];
      half8 sum = *(const half8*)(sp);
      sum = sum + *(const half8*)(sp + 512);     // slice stride 16*32
      sum = sum + *(const half8*)(sp + 1024);
      sum = sum + *(const half8*)(sp + 1536);
      sum = sum + *(const half8*)(sp + 2048);
      sum = sum + *(const half8*)(sp + 2560);
      sum = sum + *(const half8*)(sp + 3072);
      sum = sum + *(const half8*)(sp + 3584);

      const bool mt = (t == nkt - 1);
      const int  gb = 32 * t + lg * 8;     // this lane's global key base
      half8 aP;
#pragma unroll
      for (int j = 0; j < 8; ++j) {
        float p = __expf((float)sum[j] * 0.03125f);
        if (mt && (gb + j >= qbase + lr)) p = 0.0f;   // strictly-causal
        l0 += p;
        aP[j] = (_Float16)p;
      }

      // compiler has already waited lgkmcnt(0) for the Sred loads used in
      // exp, which (in-order DS) also retired tr groups 1+2
      __builtin_amdgcn_sched_barrier(0);
      MFMA2(t0, 0, 1);
      ISSUE4(t0, "4096", "4608", "5120", "5632");
      asm volatile("s_waitcnt lgkmcnt(4)" ::: "memory");
      __builtin_amdgcn_sched_barrier(0);
      MFMA2(t1, 2, 3);
      ISSUE4(t1, "6144", "6656", "7168", "7680");
      asm volatile("s_waitcnt lgkmcnt(4)" ::: "memory");
      __builtin_amdgcn_sched_barrier(0);
      MFMA2(t0, 4, 5);
      asm volatile("s_waitcnt lgkmcnt(0)" ::: "memory");   // all tr reads done
      __builtin_amdgcn_sched_barrier(0);
      MFMA2(t1, 6, 7);
    }

    // ---- restage own segment (own tr reads drained above); in flight
    //      across next QK's WAITVM0. No barrier: SredD alternates, Kbuf is
    //      wave-private ----
    if (t + 1 < nkt) {
      if constexpr (!WS) __syncthreads();   // fallback: cross-segment writes
      STAGE(t + 1);
      if constexpr (!WS) __syncthreads();
    }
  }

  BAR_LDS();   // drain last PV reads before aliased scratch writes

  // ---- l reduce (replicated across waves; reduce over lg key-groups) ----
  {
    float lt = l0 + __shfl_xor(l0, 16);
    lt += __shfl_xor(lt, 32);
    if (w == 0 && lg == 0) l_s[lr] = lt;
  }

  // ---- epilogue: per-row <x,O>, |x|^2, |O|^2 (per-wave 128-feat slice) ----
  {
#pragma unroll
    for (int j = 0; j < 4; ++j) {
      const int row = lg * 4 + j;
      const float* xr = xb + (size_t)(qbase + row) * DN + w * 128 + lr;
      float a1 = 0.f, a2 = 0.f, a3 = 0.f;
#pragma unroll
      for (int ct = 0; ct < 8; ++ct) {
        const float xv = xr[ct * 16];
        const float ov = oacc[ct][j];
        a1 += xv * ov; a2 += xv * xv; a3 += ov * ov;
      }
#pragma unroll
      for (int d = 1; d < 16; d <<= 1) {
        a1 += __shfl_xor(a1, d);
        a2 += __shfl_xor(a2, d);
        a3 += __shfl_xor(a3, d);
      }
      if (lr == 0) {
        float* e = ered + (row * 8 + w) * 4;
        e[0] = a1; e[1] = a2; e[2] = a3;
      }
    }
  }
  __syncthreads();
  if (tid < 16) {
    float SxO = 0.f, Sxx = 0.f, SOO = 0.f;
#pragma unroll
    for (int wv = 0; wv < 8; ++wv) {
      const float* e = ered + (tid * 8 + wv) * 4;
      SxO += e[0]; Sxx += e[1]; SOO += e[2];
    }
    const float lden = l_s[tid];
    float cosv = 0.0f;
    if (lden > 0.0f) {
      const float nx = fmaxf(sqrtf(Sxx), 1e-12f);
      const float nc = fmaxf(sqrtf(SOO) / lden, 1e-12f);
      cosv = (SxO / lden) / (nx * nc);
    }
    float nov = fminf(fmaxf(1.0f - cosv, 0.0f), 2.0f) * 0.5f;
    gate_s[tid] = 1.0f + alpha * tanhf(sigma * nov);
  }
  __syncthreads();
  {
#pragma unroll
    for (int j = 0; j < 4; ++j) {
      const int row = lg * 4 + j;
      const float g = gate_s[row];
      const float* xr = xb + (size_t)(qbase + row) * DN + w * 128 + lr;
      float* orow     = ob + (size_t)(qbase + row) * DN + w * 128 + lr;
#pragma unroll
      for (int ct = 0; ct < 8; ++ct) {
        const float z = xr[ct * 16] * g;
        const float u = 0.7978845608028654f * (z + 0.044715f * z * z * z);
        orow[ct * 16] = 0.5f * z * (1.0f + tanhf(u));
      }
    }
  }
}

extern "C" void kernel_launch(void* const* d_in, const int* in_sizes, int n_in,
                              void* d_out, int out_size, void* d_ws, size_t ws_size,
                              hipStream_t stream) {
  const float* x  = (const float*)d_in[0];
  const float* la = (const float*)d_in[1];
  const float* ls = (const float*)d_in[2];
  float* out = (float*)d_out;
  const size_t need = (size_t)8 * 64 * 32768 * 2;   // 32 MB f16 tile images
  if (ws_size >= need) {
    convert_x<<<dim3(8192), dim3(256), 0, stream>>>(x, (_Float16*)d_ws);
    attn_gate<true><<<dim3(1024), dim3(512), 0, stream>>>(
        x, (const _Float16*)d_ws, la, ls, out);
  } else {
    attn_gate<false><<<dim3(1024), dim3(512), 0, stream>>>(
        x, (const _Float16*)nullptr, la, ls, out);
  }
}

// Round 17
// 187.173 us; speedup vs baseline: 4.8189x; 1.1379x over previous
//
#include <hip/hip_runtime.h>
#include <math.h>

#define TN 2048
#define DN 1024

typedef __attribute__((ext_vector_type(8))) _Float16 half8;
typedef __attribute__((ext_vector_type(4))) _Float16 half4v;
typedef __attribute__((ext_vector_type(4))) float f32x4;

__device__ __forceinline__ f32x4 mfma16(half8 a, half8 b, f32x4 c) {
  return __builtin_amdgcn_mfma_f32_16x16x32_f16(a, b, c, 0, 0, 0);
}

// lgkm-only barrier: vmem staging is synced per-wave (segment-private), never
// drained at barriers.
#define BAR_LDS()  asm volatile("s_waitcnt lgkmcnt(0)\ns_barrier" ::: "memory")
#define WAITVM0()  asm volatile("s_waitcnt vmcnt(0)" ::: "memory")

// K tile image (32 keys x 1024 feats, f16, 64KB):
//   elem_off(key,f) = (f>>4)*512 + perm(key>>2)*64 + (key&3)*16 + (f&15)
//   perm(kg) = (kg&1)*4 + (kg>>1)   (tr_read lane-group lg sees keys 8*lg+j)
// Wave w's QK reads, PV tr-reads AND staging writes all live in elems
// [w*4096,(w+1)*4096) -> K staging syncs per-wave via vmcnt, no barrier.
__device__ __forceinline__ int img_off(int key, int f) {
  const int kg = key >> 2;
  const int p  = ((kg & 1) << 2) | (kg >> 1);
  return (f >> 4) * 512 + p * 64 + (key & 3) * 16 + (f & 15);
}

// x fp32 [8][2048][1024] -> f16 tile images in ws: [b*64+tile][32768 elems]
__global__ __launch_bounds__(256) void convert_x(const float* __restrict__ x,
                                                 _Float16* __restrict__ w) {
  const long long gid = (long long)blockIdx.x * 256 + threadIdx.x;
  const long long e   = gid * 8;
  const int bt   = (int)(e >> 15);
  const int et   = (int)(e & 32767);
  const int f16b = et >> 9;
  const int p    = (et >> 6) & 7;
  const int row  = (et >> 4) & 3;
  const int col0 = et & 15;
  const int kg   = ((p & 3) << 1) | (p >> 2);    // inverse perm
  const int key  = kg * 4 + row;
  const size_t xoff = ((size_t)bt * 32 + key) * DN + f16b * 16 + col0;
  float4 u0 = *(const float4*)(x + xoff);
  float4 u1 = *(const float4*)(x + xoff + 4);
  half8 h = {(_Float16)u0.x, (_Float16)u0.y, (_Float16)u0.z, (_Float16)u0.w,
             (_Float16)u1.x, (_Float16)u1.y, (_Float16)u1.z, (_Float16)u1.w};
  *(half8*)(w + e) = h;
}

#define ISSUE4(T, O0, O1, O2, O3)                                             \
  asm volatile("ds_read_b64_tr_b16 %0, %4 offset:" O0 "\n\t"                  \
               "ds_read_b64_tr_b16 %1, %4 offset:" O1 "\n\t"                  \
               "ds_read_b64_tr_b16 %2, %4 offset:" O2 "\n\t"                  \
               "ds_read_b64_tr_b16 %3, %4 offset:" O3                         \
               : "=&v"(T[0]), "=&v"(T[1]), "=&v"(T[2]), "=&v"(T[3])           \
               : "v"(ab));

#define MFMA2(T, CT0, CT1)                                                    \
  {                                                                           \
    half8 bf0 = __builtin_shufflevector(T[0], T[1], 0, 1, 2, 3, 4, 5, 6, 7);  \
    half8 bf1 = __builtin_shufflevector(T[2], T[3], 0, 1, 2, 3, 4, 5, 6, 7);  \
    oacc[CT0] = mfma16(aP, bf0, oacc[CT0]);                                   \
    oacc[CT1] = mfma16(aP, bf1, oacc[CT1]);                                   \
  }

// One block = one (batch, 16-row q-tile). 1024 blocks, q16 descending.
// 8 waves, 8-way k-split QK (swapped mfma(K,Q)). No-max softmax.
// R17 = R16 (dbuf Sred, ONE barrier/K-tile, 80KB LDS, 2 blocks/CU)
//     + XOR-swizzled Sred columns: phys_col4 = col4 ^ (lr&6).
//   - b64 QK writes: worst 4-way (cheap);
//   - b128 exp reads: contiguous, logical order (even swizzle), 2-way = free;
//   - kills R16's 2.35e7 conflicts (stride-32 8-way aliasing) at zero LDS.
template <bool WS>
__global__ __launch_bounds__(512, 4)
void attn_gate(const float* __restrict__ x, const _Float16* __restrict__ wsx,
               const float* __restrict__ pla, const float* __restrict__ pls,
               float* __restrict__ out) {
  __shared__ _Float16 Kbuf[32768];           // single K tile image   64KB
  __shared__ _Float16 SredD[2][8][16][32];   // dbuf S partials       16KB
  // post-loop scratch aliased into SredD (used only after the final BAR):
  float* l_s    = (float*)&SredD[0][0][0][0];        // 16 floats
  float* gate_s = l_s + 16;                          // 16 floats
  float* ered   = gate_s + 16;                       // 512 floats

  const int tid = threadIdx.x;
  const int w   = tid >> 6;       // wave 0..7 == kq (k-eighth, 128 feats)
  const int l   = tid & 63;
  const int lr  = l & 15;
  const int lg  = l >> 4;
  const int kq  = w;

  const int b   = blockIdx.x & 7;            // batch -> XCD
  const int q16 = 127 - (blockIdx.x >> 3);   // long blocks dispatched first
  const int qbase = q16 * 16;
  const int nkt   = (qbase + 14) / 32 + 1;   // 32-key tiles, strictly causal

  const float alpha = log1pf(expf(pla[0]));
  const float sigma = log1pf(expf(pls[0]));

  const float* xb = x + (size_t)b * TN * DN;
  float*       ob = out + (size_t)b * TN * DN;

  // QK A-frag offsets (K as A-operand): keys lr and 16+lr
  const int kg0 = lr >> 2;
  const int bk0 = ((((kg0 & 1) << 2) | (kg0 >> 1)) << 6) + (lr & 3) * 16 + (lg & 1) * 8;
  const int kg1 = 4 + (lr >> 2);
  const int bk1 = ((((kg1 & 1) << 2) | (kg1 >> 1)) << 6) + (lr & 3) * 16 + (lg & 1) * 8;

  // Sred swizzle offsets (elems), loop-invariant: phys_col4 = col4 ^ (lr&6)
  const int swzA = (lg ^ (lr & 6)) << 2;         // write hA (col4 = lg)
  const int swzB = ((4 + lg) ^ (lr & 6)) << 2;   // write hB (col4 = 4+lg)
  const int swzR = ((lg * 2) ^ (lr & 6)) << 2;   // read b128 (col4 = 2lg,2lg+1)

  auto STAGE = [&](int t) {   // WS: wave w writes ONLY its own segment
    if constexpr (WS) {
      const _Float16* tn = wsx + (size_t)(b * 64 + t) * 32768;
#pragma unroll
      for (int i = 0; i < 8; ++i)
        __builtin_amdgcn_global_load_lds(
            (const __attribute__((address_space(1))) void*)(tn + w * 4096 + i * 512 + l * 8),
            (__attribute__((address_space(3))) void*)(&Kbuf[w * 4096 + i * 512]), 16, 0, 0);
    } else {
      const int skey = tid >> 4, sc = tid & 15;
      const float* kp = xb + (size_t)(t * 32 + skey) * DN + sc * 4;
#pragma unroll
      for (int j = 0; j < 16; ++j) {
        const int f = sc * 4 + 64 * j;
        float4 v = *(const float4*)(kp + 64 * j);
        half4v h = {(_Float16)v.x, (_Float16)v.y, (_Float16)v.z, (_Float16)v.w};
        *(half4v*)&Kbuf[img_off(skey, f)] = h;
      }
    }
  };

  STAGE(0);

  // ---- Q fragments: row lr of this 16-row tile, k-eighth (16 VGPR) ----
  half8 qf[4];
  if constexpr (WS) {
    const _Float16* qtile = wsx + (size_t)(b * 64 + (q16 >> 1)) * 32768;
    const int qrow = (q16 & 1) * 16 + lr;
    const int g0   = qrow >> 2;
    const int qp   = (((g0 & 1) << 2) | (g0 >> 1)) * 64 + (qrow & 3) * 16 + (lg & 1) * 8;
#pragma unroll
    for (int s = 0; s < 4; ++s)
      qf[s] = *(const half8*)&qtile[(kq * 8 + s * 2 + (lg >> 1)) * 512 + qp];
  } else {
#pragma unroll
    for (int s = 0; s < 4; ++s) {
      const float* qp = xb + (size_t)(qbase + lr) * DN + kq * 128 + s * 32 + lg * 8;
      float4 a = ((const float4*)qp)[0];
      float4 c = ((const float4*)qp)[1];
      half8 h;
      h[0]=(_Float16)a.x; h[1]=(_Float16)a.y; h[2]=(_Float16)a.z; h[3]=(_Float16)a.w;
      h[4]=(_Float16)c.x; h[5]=(_Float16)c.y; h[6]=(_Float16)c.z; h[7]=(_Float16)c.w;
      qf[s] = h;
    }
  }

  f32x4 oacc[8];
#pragma unroll
  for (int ct = 0; ct < 8; ++ct) oacc[ct] = f32x4{0.f, 0.f, 0.f, 0.f};
  float l0 = 0.0f;

  if constexpr (!WS) __syncthreads();   // fallback staging is cross-segment

  for (int t = 0; t < nkt; ++t) {
    if constexpr (WS) WAITVM0();   // own-segment stage(t) landed

    // ---- QK^T (swapped): D[key_local][q-row]; lane -> 4 consecutive keys ----
    {
      f32x4 sA = f32x4{0.f,0.f,0.f,0.f};   // keys 0..15
      f32x4 sB = f32x4{0.f,0.f,0.f,0.f};   // keys 16..31
#pragma unroll
      for (int s = 0; s < 4; ++s) {
        const int base = (kq * 8 + s * 2 + (lg >> 1)) * 512;
        half8 bf0 = *(const half8*)&Kbuf[base + bk0];
        half8 bf1 = *(const half8*)&Kbuf[base + bk1];
        sA = mfma16(bf0, qf[s], sA);
        sB = mfma16(bf1, qf[s], sB);
      }
      half4v hA = {(_Float16)sA[0], (_Float16)sA[1], (_Float16)sA[2], (_Float16)sA[3]};
      half4v hB = {(_Float16)sB[0], (_Float16)sB[1], (_Float16)sB[2], (_Float16)sB[3]};
      _Float16* srow = &SredD[t & 1][kq][lr][0];
      *(half4v*)(srow + swzA) = hA;   // logical cols lg*4..+3
      *(half4v*)(srow + swzB) = hB;   // logical cols 16+lg*4..+3
    }
    BAR_LDS();   // (A) SredD[t&1] ready — the ONLY barrier per tile

    // ---- fused exp + PV (tr groups 1+2 issued early: latency hides under
    //      Sred reads + exp) ----
    {
      const uint32_t ab = (uint32_t)(uintptr_t)(void*)&Kbuf[w * 4096 + l * 4];
      half4v t0[4], t1[4];
      ISSUE4(t0, "0", "512", "1024", "1536");
      ISSUE4(t1, "2048", "2560", "3072", "3584");

      const _Float16* sp = &SredD[t & 1][0][lr][0] + swzR;
      half8 sum = *(const half8*)(sp);
      sum = sum + *(const half8*)(sp + 512);     // slice stride 16*32
      sum = sum + *(const half8*)(sp + 1024);
      sum = sum + *(const half8*)(sp + 1536);
      sum = sum + *(const half8*)(sp + 2048);
      sum = sum + *(const half8*)(sp + 2560);
      sum = sum + *(const half8*)(sp + 3072);
      sum = sum + *(const half8*)(sp + 3584);

      const bool mt = (t == nkt - 1);
      const int  gb = 32 * t + lg * 8;     // this lane's global key base
      half8 aP;
#pragma unroll
      for (int j = 0; j < 8; ++j) {
        float p = __expf((float)sum[j] * 0.03125f);
        if (mt && (gb + j >= qbase + lr)) p = 0.0f;   // strictly-causal
        l0 += p;
        aP[j] = (_Float16)p;
      }

      // compiler has already waited lgkmcnt(0) for the Sred loads used in
      // exp, which (in-order DS) also retired tr groups 1+2
      __builtin_amdgcn_sched_barrier(0);
      MFMA2(t0, 0, 1);
      ISSUE4(t0, "4096", "4608", "5120", "5632");
      asm volatile("s_waitcnt lgkmcnt(4)" ::: "memory");
      __builtin_amdgcn_sched_barrier(0);
      MFMA2(t1, 2, 3);
      ISSUE4(t1, "6144", "6656", "7168", "7680");
      asm volatile("s_waitcnt lgkmcnt(4)" ::: "memory");
      __builtin_amdgcn_sched_barrier(0);
      MFMA2(t0, 4, 5);
      asm volatile("s_waitcnt lgkmcnt(0)" ::: "memory");   // all tr reads done
      __builtin_amdgcn_sched_barrier(0);
      MFMA2(t1, 6, 7);
    }

    // ---- restage own segment (own tr reads drained above); in flight
    //      across next QK's WAITVM0. No barrier: SredD alternates, Kbuf is
    //      wave-private ----
    if (t + 1 < nkt) {
      if constexpr (!WS) __syncthreads();   // fallback: cross-segment writes
      STAGE(t + 1);
      if constexpr (!WS) __syncthreads();
    }
  }

  BAR_LDS();   // drain last PV reads before aliased scratch writes

  // ---- l reduce (replicated across waves; reduce over lg key-groups) ----
  {
    float lt = l0 + __shfl_xor(l0, 16);
    lt += __shfl_xor(lt, 32);
    if (w == 0 && lg == 0) l_s[lr] = lt;
  }

  // ---- epilogue: per-row <x,O>, |x|^2, |O|^2 (per-wave 128-feat slice) ----
  {
#pragma unroll
    for (int j = 0; j < 4; ++j) {
      const int row = lg * 4 + j;
      const float* xr = xb + (size_t)(qbase + row) * DN + w * 128 + lr;
      float a1 = 0.f, a2 = 0.f, a3 = 0.f;
#pragma unroll
      for (int ct = 0; ct < 8; ++ct) {
        const float xv = xr[ct * 16];
        const float ov = oacc[ct][j];
        a1 += xv * ov; a2 += xv * xv; a3 += ov * ov;
      }
#pragma unroll
      for (int d = 1; d < 16; d <<= 1) {
        a1 += __shfl_xor(a1, d);
        a2 += __shfl_xor(a2, d);
        a3 += __shfl_xor(a3, d);
      }
      if (lr == 0) {
        float* e = ered + (row * 8 + w) * 4;
        e[0] = a1; e[1] = a2; e[2] = a3;
      }
    }
  }
  __syncthreads();
  if (tid < 16) {
    float SxO = 0.f, Sxx = 0.f, SOO = 0.f;
#pragma unroll
    for (int wv = 0; wv < 8; ++wv) {
      const float* e = ered + (tid * 8 + wv) * 4;
      SxO += e[0]; Sxx += e[1]; SOO += e[2];
    }
    const float lden = l_s[tid];
    float cosv = 0.0f;
    if (lden > 0.0f) {
      const float nx = fmaxf(sqrtf(Sxx), 1e-12f);
      const float nc = fmaxf(sqrtf(SOO) / lden, 1e-12f);
      cosv = (SxO / lden) / (nx * nc);
    }
    float nov = fminf(fmaxf(1.0f - cosv, 0.0f), 2.0f) * 0.5f;
    gate_s[tid] = 1.0f + alpha * tanhf(sigma * nov);
  }
  __syncthreads();
  {
#pragma unroll
    for (int j = 0; j < 4; ++j) {
      const int row = lg * 4 + j;
      const float g = gate_s[row];
      const float* xr = xb + (size_t)(qbase + row) * DN + w * 128 + lr;
      float* orow     = ob + (size_t)(qbase + row) * DN + w * 128 + lr;
#pragma unroll
      for (int ct = 0; ct < 8; ++ct) {
        const float z = xr[ct * 16] * g;
        const float u = 0.7978845608028654f * (z + 0.044715f * z * z * z);
        orow[ct * 16] = 0.5f * z * (1.0f + tanhf(u));
      }
    }
  }
}

extern "C" void kernel_launch(void* const* d_in, const int* in_sizes, int n_in,
                              void* d_out, int out_size, void* d_ws, size_t ws_size,
                              hipStream_t stream) {
  const float* x  = (const float*)d_in[0];
  const float* la = (const float*)d_in[1];
  const float* ls = (const float*)d_in[2];
  float* out = (float*)d_out;
  const size_t need = (size_t)8 * 64 * 32768 * 2;   // 32 MB f16 tile images
  if (ws_size >= need) {
    convert_x<<<dim3(8192), dim3(256), 0, stream>>>(x, (_Float16*)d_ws);
    attn_gate<true><<<dim3(1024), dim3(512), 0, stream>>>(
        x, (const _Float16*)d_ws, la, ls, out);
  } else {
    attn_gate<false><<<dim3(1024), dim3(512), 0, stream>>>(
        x, (const _Float16*)nullptr, la, ls, out);
  }
}

// Round 18
// 184.974 us; speedup vs baseline: 4.8761x; 1.0119x over previous
//
#include <hip/hip_runtime.h>
#include <math.h>

#define TN 2048
#define DN 1024

typedef __attribute__((ext_vector_type(8))) _Float16 half8;
typedef __attribute__((ext_vector_type(4))) _Float16 half4v;
typedef __attribute__((ext_vector_type(2))) _Float16 half2v;
typedef __attribute__((ext_vector_type(4))) float f32x4;

__device__ __forceinline__ f32x4 mfma16(half8 a, half8 b, f32x4 c) {
  return __builtin_amdgcn_mfma_f32_16x16x32_f16(a, b, c, 0, 0, 0);
}

// lgkm-only barrier: vmem staging is synced per-wave (segment-private), never
// drained at barriers.
#define BAR_LDS()  asm volatile("s_waitcnt lgkmcnt(0)\ns_barrier" ::: "memory")
#define WAITVM0()  asm volatile("s_waitcnt vmcnt(0)" ::: "memory")

// K tile image (32 keys x 1024 feats, f16, 64KB):
//   elem_off(key,f) = (f>>4)*512 + perm(key>>2)*64 + (key&3)*16 + (f&15)
//   perm(kg) = (kg&1)*4 + (kg>>1)   (tr_read lane-group lg sees keys 8*lg+j)
// Wave w's QK reads, PV tr-reads AND staging writes all live in elems
// [w*4096,(w+1)*4096) -> K staging syncs per-wave via vmcnt, no barrier.
__device__ __forceinline__ int img_off(int key, int f) {
  const int kg = key >> 2;
  const int p  = ((kg & 1) << 2) | (kg >> 1);
  return (f >> 4) * 512 + p * 64 + (key & 3) * 16 + (f & 15);
}

// x fp32 [8][2048][1024] -> f16 tile images in ws: [b*64+tile][32768 elems]
__global__ __launch_bounds__(256) void convert_x(const float* __restrict__ x,
                                                 _Float16* __restrict__ w) {
  const long long gid = (long long)blockIdx.x * 256 + threadIdx.x;
  const long long e   = gid * 8;
  const int bt   = (int)(e >> 15);
  const int et   = (int)(e & 32767);
  const int f16b = et >> 9;
  const int p    = (et >> 6) & 7;
  const int row  = (et >> 4) & 3;
  const int col0 = et & 15;
  const int kg   = ((p & 3) << 1) | (p >> 2);    // inverse perm
  const int key  = kg * 4 + row;
  const size_t xoff = ((size_t)bt * 32 + key) * DN + f16b * 16 + col0;
  float4 u0 = *(const float4*)(x + xoff);
  float4 u1 = *(const float4*)(x + xoff + 4);
  half8 h = {(_Float16)u0.x, (_Float16)u0.y, (_Float16)u0.z, (_Float16)u0.w,
             (_Float16)u1.x, (_Float16)u1.y, (_Float16)u1.z, (_Float16)u1.w};
  *(half8*)(w + e) = h;
}

#define ISSUE4(T, O0, O1, O2, O3)                                             \
  asm volatile("ds_read_b64_tr_b16 %0, %4 offset:" O0 "\n\t"                  \
               "ds_read_b64_tr_b16 %1, %4 offset:" O1 "\n\t"                  \
               "ds_read_b64_tr_b16 %2, %4 offset:" O2 "\n\t"                  \
               "ds_read_b64_tr_b16 %3, %4 offset:" O3                         \
               : "=&v"(T[0]), "=&v"(T[1]), "=&v"(T[2]), "=&v"(T[3])           \
               : "v"(ab));

#define MFMA2(T, CT0, CT1)                                                    \
  {                                                                           \
    half8 bf0 = __builtin_shufflevector(T[0], T[1], 0, 1, 2, 3, 4, 5, 6, 7);  \
    half8 bf1 = __builtin_shufflevector(T[2], T[3], 0, 1, 2, 3, 4, 5, 6, 7);  \
    oacc[CT0] = mfma16(aP, bf0, oacc[CT0]);                                   \
    oacc[CT1] = mfma16(aP, bf1, oacc[CT1]);                                   \
  }

// One block = one (batch, 16-row q-tile). 1024 blocks, q16 descending.
// 8 waves, 8-way k-split QK (swapped mfma(K,Q)). No-max softmax.
// R18 = R17 (dbuf Sred, 1 barrier/K-tile, XOR swizzle, 80KB, 2 blocks/CU)
//   + STAGE(t+1) moved MID-PHASE: all 16 tr reads issued right after the
//     barrier, drained, then stage issues -> ~500cy of exp+PV+QK cover
//     (was issued at loop end and waited at loop top = fully exposed).
//   + exp trim: 1/32*log2e folded into qf (f32-precision, one-time),
//     __builtin_amdgcn_exp2f (no per-j mul), cvt_pkrtz packing, depth-3
//     slice-sum tree.
template <bool WS>
__global__ __launch_bounds__(512, 4)
void attn_gate(const float* __restrict__ x, const _Float16* __restrict__ wsx,
               const float* __restrict__ pla, const float* __restrict__ pls,
               float* __restrict__ out) {
  __shared__ _Float16 Kbuf[32768];           // single K tile image   64KB
  __shared__ _Float16 SredD[2][8][16][32];   // dbuf S partials       16KB
  // post-loop scratch aliased into SredD (used only after the final BAR):
  float* l_s    = (float*)&SredD[0][0][0][0];        // 16 floats
  float* gate_s = l_s + 16;                          // 16 floats
  float* ered   = gate_s + 16;                       // 512 floats

  const int tid = threadIdx.x;
  const int w   = tid >> 6;       // wave 0..7 == kq (k-eighth, 128 feats)
  const int l   = tid & 63;
  const int lr  = l & 15;
  const int lg  = l >> 4;
  const int kq  = w;

  const int b   = blockIdx.x & 7;            // batch -> XCD
  const int q16 = 127 - (blockIdx.x >> 3);   // long blocks dispatched first
  const int qbase = q16 * 16;
  const int nkt   = (qbase + 14) / 32 + 1;   // 32-key tiles, strictly causal

  const float alpha = log1pf(expf(pla[0]));
  const float sigma = log1pf(expf(pls[0]));
  const float cs    = 0.0450842201f;   // (1/32) * log2(e): exp(s/32)=exp2(s*cs)

  const float* xb = x + (size_t)b * TN * DN;
  float*       ob = out + (size_t)b * TN * DN;

  // QK A-frag offsets (K as A-operand): keys lr and 16+lr
  const int kg0 = lr >> 2;
  const int bk0 = ((((kg0 & 1) << 2) | (kg0 >> 1)) << 6) + (lr & 3) * 16 + (lg & 1) * 8;
  const int kg1 = 4 + (lr >> 2);
  const int bk1 = ((((kg1 & 1) << 2) | (kg1 >> 1)) << 6) + (lr & 3) * 16 + (lg & 1) * 8;

  // Sred swizzle offsets (elems), loop-invariant: phys_col4 = col4 ^ (lr&6)
  const int swzA = (lg ^ (lr & 6)) << 2;         // write hA (col4 = lg)
  const int swzB = ((4 + lg) ^ (lr & 6)) << 2;   // write hB (col4 = 4+lg)
  const int swzR = ((lg * 2) ^ (lr & 6)) << 2;   // read b128 (col4 = 2lg,2lg+1)

  auto STAGE = [&](int t) {   // WS: wave w writes ONLY its own segment
    if constexpr (WS) {
      const _Float16* tn = wsx + (size_t)(b * 64 + t) * 32768;
#pragma unroll
      for (int i = 0; i < 8; ++i)
        __builtin_amdgcn_global_load_lds(
            (const __attribute__((address_space(1))) void*)(tn + w * 4096 + i * 512 + l * 8),
            (__attribute__((address_space(3))) void*)(&Kbuf[w * 4096 + i * 512]), 16, 0, 0);
    } else {
      const int skey = tid >> 4, sc = tid & 15;
      const float* kp = xb + (size_t)(t * 32 + skey) * DN + sc * 4;
#pragma unroll
      for (int j = 0; j < 16; ++j) {
        const int f = sc * 4 + 64 * j;
        float4 v = *(const float4*)(kp + 64 * j);
        half4v h = {(_Float16)v.x, (_Float16)v.y, (_Float16)v.z, (_Float16)v.w};
        *(half4v*)&Kbuf[img_off(skey, f)] = h;
      }
    }
  };

  STAGE(0);

  // ---- Q fragments: row lr of this 16-row tile, k-eighth (16 VGPR),
  //      with exp2 scale folded in (f32-precision rescale, one-time) ----
  half8 qf[4];
  if constexpr (WS) {
    const _Float16* qtile = wsx + (size_t)(b * 64 + (q16 >> 1)) * 32768;
    const int qrow = (q16 & 1) * 16 + lr;
    const int g0   = qrow >> 2;
    const int qp   = (((g0 & 1) << 2) | (g0 >> 1)) * 64 + (qrow & 3) * 16 + (lg & 1) * 8;
#pragma unroll
    for (int s = 0; s < 4; ++s) {
      half8 h = *(const half8*)&qtile[(kq * 8 + s * 2 + (lg >> 1)) * 512 + qp];
#pragma unroll
      for (int j = 0; j < 8; ++j) h[j] = (_Float16)((float)h[j] * cs);
      qf[s] = h;
    }
  } else {
#pragma unroll
    for (int s = 0; s < 4; ++s) {
      const float* qp = xb + (size_t)(qbase + lr) * DN + kq * 128 + s * 32 + lg * 8;
      float4 a = ((const float4*)qp)[0];
      float4 c = ((const float4*)qp)[1];
      half8 h;
      h[0]=(_Float16)(a.x*cs); h[1]=(_Float16)(a.y*cs);
      h[2]=(_Float16)(a.z*cs); h[3]=(_Float16)(a.w*cs);
      h[4]=(_Float16)(c.x*cs); h[5]=(_Float16)(c.y*cs);
      h[6]=(_Float16)(c.z*cs); h[7]=(_Float16)(c.w*cs);
      qf[s] = h;
    }
  }

  f32x4 oacc[8];
#pragma unroll
  for (int ct = 0; ct < 8; ++ct) oacc[ct] = f32x4{0.f, 0.f, 0.f, 0.f};
  float l0 = 0.0f;

  if constexpr (!WS) __syncthreads();   // fallback staging is cross-segment

  for (int t = 0; t < nkt; ++t) {
    if constexpr (WS) WAITVM0();   // own-segment stage(t) landed (covered by
                                   // prior iter's exp+PV+QK since R18)

    // ---- QK^T (swapped): D[key_local][q-row]; lane -> 4 consecutive keys ----
    {
      f32x4 sA = f32x4{0.f,0.f,0.f,0.f};   // keys 0..15
      f32x4 sB = f32x4{0.f,0.f,0.f,0.f};   // keys 16..31
#pragma unroll
      for (int s = 0; s < 4; ++s) {
        const int base = (kq * 8 + s * 2 + (lg >> 1)) * 512;
        half8 bf0 = *(const half8*)&Kbuf[base + bk0];
        half8 bf1 = *(const half8*)&Kbuf[base + bk1];
        sA = mfma16(bf0, qf[s], sA);
        sB = mfma16(bf1, qf[s], sB);
      }
      half4v hA = {(_Float16)sA[0], (_Float16)sA[1], (_Float16)sA[2], (_Float16)sA[3]};
      half4v hB = {(_Float16)sB[0], (_Float16)sB[1], (_Float16)sB[2], (_Float16)sB[3]};
      _Float16* srow = &SredD[t & 1][kq][lr][0];
      *(half4v*)(srow + swzA) = hA;   // logical cols lg*4..+3
      *(half4v*)(srow + swzB) = hB;   // logical cols 16+lg*4..+3
    }
    BAR_LDS();   // (A) SredD[t&1] ready — the ONLY barrier per tile

    // ---- PV phase: tr reads first, stage mid-phase, exp, MFMA ----
    {
      const uint32_t ab = (uint32_t)(uintptr_t)(void*)&Kbuf[w * 4096 + l * 4];
      half4v t0[4], t1[4], t2[4], t3[4];
      ISSUE4(t0, "0", "512", "1024", "1536");
      ISSUE4(t1, "2048", "2560", "3072", "3584");
      ISSUE4(t2, "4096", "4608", "5120", "5632");
      ISSUE4(t3, "6144", "6656", "7168", "7680");

      // depth-3 slice-sum tree (independent b128 loads)
      const _Float16* sp = &SredD[t & 1][0][lr][0] + swzR;
      half8 s0 = *(const half8*)(sp)        + *(const half8*)(sp + 512);
      half8 s1 = *(const half8*)(sp + 1024) + *(const half8*)(sp + 1536);
      half8 s2 = *(const half8*)(sp + 2048) + *(const half8*)(sp + 2560);
      half8 s3 = *(const half8*)(sp + 3072) + *(const half8*)(sp + 3584);
      half8 sum = (s0 + s1) + (s2 + s3);

      // drain ALL LDS reads (tr groups + Sred) -> own Kbuf segment reusable
      asm volatile("s_waitcnt lgkmcnt(0)" ::: "memory");
      __builtin_amdgcn_sched_barrier(0);

      // stage(t+1) NOW: in flight under exp + 16 MFMA + next QK
      if constexpr (WS) {
        if (t + 1 < nkt) STAGE(t + 1);
      }

      // exp block: exp2 with pre-folded scale, pkrtz packing
      const bool mt = (t == nkt - 1);
      const int  gb = 32 * t + lg * 8;     // this lane's global key base
      union { uint32_t u[4]; half8 h; } ap;
#pragma unroll
      for (int k = 0; k < 4; ++k) {
        float p0 = __builtin_amdgcn_exp2f((float)sum[2 * k]);
        float p1 = __builtin_amdgcn_exp2f((float)sum[2 * k + 1]);
        if (mt) {
          if (gb + 2 * k     >= qbase + lr) p0 = 0.0f;   // strictly-causal
          if (gb + 2 * k + 1 >= qbase + lr) p1 = 0.0f;
        }
        l0 += p0 + p1;
        ap.u[k] = __builtin_bit_cast(uint32_t,
                                     __builtin_amdgcn_cvt_pkrtz(p0, p1));
      }
      half8 aP = ap.h;

      __builtin_amdgcn_sched_barrier(0);   // MFMAs stay below stage issue
      MFMA2(t0, 0, 1);
      MFMA2(t1, 2, 3);
      MFMA2(t2, 4, 5);
      MFMA2(t3, 6, 7);
    }

    // fallback path: cross-segment staging needs block-wide ordering
    if constexpr (!WS) {
      if (t + 1 < nkt) {
        __syncthreads();
        STAGE(t + 1);
        __syncthreads();
      }
    }
  }

  BAR_LDS();   // drain last PV reads before aliased scratch writes

  // ---- l reduce (replicated across waves; reduce over lg key-groups) ----
  {
    float lt = l0 + __shfl_xor(l0, 16);
    lt += __shfl_xor(lt, 32);
    if (w == 0 && lg == 0) l_s[lr] = lt;
  }

  // ---- epilogue: per-row <x,O>, |x|^2, |O|^2 (per-wave 128-feat slice) ----
  {
#pragma unroll
    for (int j = 0; j < 4; ++j) {
      const int row = lg * 4 + j;
      const float* xr = xb + (size_t)(qbase + row) * DN + w * 128 + lr;
      float a1 = 0.f, a2 = 0.f, a3 = 0.f;
#pragma unroll
      for (int ct = 0; ct < 8; ++ct) {
        const float xv = xr[ct * 16];
        const float ov = oacc[ct][j];
        a1 += xv * ov; a2 += xv * xv; a3 += ov * ov;
      }
#pragma unroll
      for (int d = 1; d < 16; d <<= 1) {
        a1 += __shfl_xor(a1, d);
        a2 += __shfl_xor(a2, d);
        a3 += __shfl_xor(a3, d);
      }
      if (lr == 0) {
        float* e = ered + (row * 8 + w) * 4;
        e[0] = a1; e[1] = a2; e[2] = a3;
      }
    }
  }
  __syncthreads();
  if (tid < 16) {
    float SxO = 0.f, Sxx = 0.f, SOO = 0.f;
#pragma unroll
    for (int wv = 0; wv < 8; ++wv) {
      const float* e = ered + (tid * 8 + wv) * 4;
      SxO += e[0]; Sxx += e[1]; SOO += e[2];
    }
    const float lden = l_s[tid];
    float cosv = 0.0f;
    if (lden > 0.0f) {
      const float nx = fmaxf(sqrtf(Sxx), 1e-12f);
      const float nc = fmaxf(sqrtf(SOO) / lden, 1e-12f);
      cosv = (SxO / lden) / (nx * nc);
    }
    float nov = fminf(fmaxf(1.0f - cosv, 0.0f), 2.0f) * 0.5f;
    gate_s[tid] = 1.0f + alpha * tanhf(sigma * nov);
  }
  __syncthreads();
  {
#pragma unroll
    for (int j = 0; j < 4; ++j) {
      const int row = lg * 4 + j;
      const float g = gate_s[row];
      const float* xr = xb + (size_t)(qbase + row) * DN + w * 128 + lr;
      float* orow     = ob + (size_t)(qbase + row) * DN + w * 128 + lr;
#pragma unroll
      for (int ct = 0; ct < 8; ++ct) {
        const float z = xr[ct * 16] * g;
        const float u = 0.7978845608028654f * (z + 0.044715f * z * z * z);
        orow[ct * 16] = 0.5f * z * (1.0f + tanhf(u));
      }
    }
  }
}

extern "C" void kernel_launch(void* const* d_in, const int* in_sizes, int n_in,
                              void* d_out, int out_size, void* d_ws, size_t ws_size,
                              hipStream_t stream) {
  const float* x  = (const float*)d_in[0];
  const float* la = (const float*)d_in[1];
  const float* ls = (const float*)d_in[2];
  float* out = (float*)d_out;
  const size_t need = (size_t)8 * 64 * 32768 * 2;   // 32 MB f16 tile images
  if (ws_size >= need) {
    convert_x<<<dim3(8192), dim3(256), 0, stream>>>(x, (_Float16*)d_ws);
    attn_gate<true><<<dim3(1024), dim3(512), 0, stream>>>(
        x, (const _Float16*)d_ws, la, ls, out);
  } else {
    attn_gate<false><<<dim3(1024), dim3(512), 0, stream>>>(
        x, (const _Float16*)nullptr, la, ls, out);
  }
}